// Round 2
// baseline (5476.620 us; speedup 1.0000x reference)
//
#include <hip/hip_runtime.h>

typedef short s16x8 __attribute__((ext_vector_type(8)));
typedef float f32x4 __attribute__((ext_vector_type(4)));
typedef unsigned short u16x4 __attribute__((ext_vector_type(4)));

static __device__ __forceinline__ unsigned short f2bf(float f) {
    union { float f; unsigned u; } v; v.f = f;
    unsigned r = v.u + 0x7FFF + ((v.u >> 16) & 1);   // round-nearest-even
    return (unsigned short)(r >> 16);
}
static __device__ __forceinline__ float bf2f(unsigned short u) {
    union { unsigned u; float f; } v; v.u = ((unsigned)u) << 16;
    return v.f;
}

// ---------------------------------------------------------------------------
// k_lc: locally-connected 3x3 + ReLU + maxpool2, 4 images per block.
// Thread t owns 4 consecutive positions (row r = t>>3, cols c0..c0+3).
// Every w_lc read is a coalesced float4 feeding 16 FMA (4 img x 4 pos).
// Output: y1g[b][o][pr][pc] bf16 (16x16 pooled).
// ---------------------------------------------------------------------------
__global__ __launch_bounds__(256, 3) void k_lc(
    const float* __restrict__ x,      // (4096-half base) (b,3,32,32)
    const float* __restrict__ w_lc,   // (32,3,9,32,32)
    const float* __restrict__ b_lc,   // (32,32,32)
    unsigned short* __restrict__ y1g) // (2048,32,16,16) bf16, local b
{
    __shared__ float xs[4][3][32][32];   // 48 KB
    const int t = threadIdx.x;
    const int b0 = blockIdx.x * 4;

    {   // stage 4 images, coalesced float4
        const float4* s = (const float4*)(x + (size_t)b0 * 3072);
        float4* d = (float4*)&xs[0][0][0][0];
        for (int i = t; i < 3072; i += 256) d[i] = s[i];
    }
    __syncthreads();

    const int r  = t >> 3;           // 0..31
    const int c0 = (t & 7) * 4;      // 0,4,...,28

    for (int oc4 = 0; oc4 < 8; ++oc4) {
        float acc[4][4][4];          // [o'][img][q]
        #pragma unroll
        for (int op = 0; op < 4; ++op) {
            const float4 bv = *(const float4*)&b_lc[((oc4 * 4 + op) * 32 + r) * 32 + c0];
            #pragma unroll
            for (int img = 0; img < 4; ++img) {
                acc[op][img][0] = bv.x; acc[op][img][1] = bv.y;
                acc[op][img][2] = bv.z; acc[op][img][3] = bv.w;
            }
        }
        #pragma unroll
        for (int c = 0; c < 3; ++c) {
            #pragma unroll
            for (int di = 0; di < 3; ++di) {
                const int ii = r + di - 1;
                float xrow[4][6];
                if ((unsigned)ii < 32u) {
                    #pragma unroll
                    for (int img = 0; img < 4; ++img) {
                        xrow[img][0] = (c0 > 0) ? xs[img][c][ii][c0 - 1] : 0.f;
                        const float4 xm = *(const float4*)&xs[img][c][ii][c0];
                        xrow[img][1] = xm.x; xrow[img][2] = xm.y;
                        xrow[img][3] = xm.z; xrow[img][4] = xm.w;
                        xrow[img][5] = (c0 < 28) ? xs[img][c][ii][c0 + 4] : 0.f;
                    }
                } else {
                    #pragma unroll
                    for (int img = 0; img < 4; ++img)
                        #pragma unroll
                        for (int q = 0; q < 6; ++q) xrow[img][q] = 0.f;
                }
                #pragma unroll
                for (int op = 0; op < 4; ++op) {
                    const int o = oc4 * 4 + op;
                    #pragma unroll
                    for (int dj = 0; dj < 3; ++dj) {
                        const float4 wv = *(const float4*)&w_lc[
                            (((size_t)o * 3 + c) * 9 + di * 3 + dj) * 1024 + r * 32 + c0];
                        #pragma unroll
                        for (int img = 0; img < 4; ++img) {
                            acc[op][img][0] += xrow[img][dj + 0] * wv.x;
                            acc[op][img][1] += xrow[img][dj + 1] * wv.y;
                            acc[op][img][2] += xrow[img][dj + 2] * wv.z;
                            acc[op][img][3] += xrow[img][dj + 3] * wv.w;
                        }
                    }
                }
            }
        }
        // pool 2x2 + relu, store bf16 pairs
        #pragma unroll
        for (int op = 0; op < 4; ++op) {
            const int o = oc4 * 4 + op;
            #pragma unroll
            for (int img = 0; img < 4; ++img) {
                float h0 = fmaxf(acc[op][img][0], acc[op][img][1]);
                float h1 = fmaxf(acc[op][img][2], acc[op][img][3]);
                const float v0 = __shfl_xor(h0, 8, 64);
                const float v1 = __shfl_xor(h1, 8, 64);
                if (!(r & 1)) {
                    const float p0 = fmaxf(fmaxf(h0, v0), 0.f);
                    const float p1 = fmaxf(fmaxf(h1, v1), 0.f);
                    const unsigned pk = (unsigned)f2bf(p0) | ((unsigned)f2bf(p1) << 16);
                    *(unsigned*)&y1g[(((size_t)(b0 + img) * 32 + o) * 256)
                                     + (r >> 1) * 16 + (c0 >> 1)] = pk;
                }
            }
        }
    }
}

// ---------------------------------------------------------------------------
// k_conv: 3x3 SAME conv (32->64) + bias + ReLU + maxpool2 via bf16 MFMA.
// Block = 4 images (1 wave each). K = 288 ordered (kk, ic): each K-slice of
// the im2col matrix is a shifted window of the zero-padded LDS tile
// y1t[18][18][40] (stride 80 B: conflict-optimal b128 reads, 16B aligned).
// ---------------------------------------------------------------------------
__global__ __launch_bounds__(256, 1) void k_conv(
    const unsigned short* __restrict__ y1g, // (2048,32,16,16) bf16 local b
    const float* __restrict__ w_conv,       // (64,32,3,3)
    const float* __restrict__ b_conv,       // (64,)
    unsigned short* __restrict__ p2)        // (half:2048,64,8,8) bf16
{
    __shared__ __align__(16) unsigned short y1t[4][18][18][40];  // 103,680 B
    __shared__ __align__(16) unsigned short wt[9][64][40];       //  46,080 B
    __shared__ __align__(16) unsigned short pbuf[4][1024];       //   8,192 B
    const int t = threadIdx.x;
    const int b0 = blockIdx.x * 4;

    {   // zero y1t (borders + ic pad) and wt (ic pad)
        unsigned short* p = &y1t[0][0][0][0];
        for (int i = t * 8; i < 4 * 18 * 18 * 40; i += 2048) {
            s16x8 z = {0, 0, 0, 0, 0, 0, 0, 0};
            *(s16x8*)(p + i) = z;
        }
        unsigned short* q = &wt[0][0][0];
        for (int i = t * 8; i < 9 * 64 * 40; i += 2048) {
            s16x8 z = {0, 0, 0, 0, 0, 0, 0, 0};
            *(s16x8*)(q + i) = z;
        }
    }
    __syncthreads();

    // stage y1 -> y1t[img][r+1][c+1][ic] (transpose to ic-inner, o-pairs -> b32)
    for (int it = 0; it < 8; ++it) {
        const int idx = t + it * 256;      // 0..2047
        const int img = idx >> 9;
        const int rem = idx & 511;
        const int o2 = rem >> 5;           // 0..15 (o pair)
        const int r2 = (rem >> 1) & 15;
        const int c8 = rem & 1;
        const unsigned short* src =
            y1g + (((size_t)(b0 + img) * 32 + o2 * 2) * 256 + r2 * 16 + c8 * 8);
        const s16x8 v0 = *(const s16x8*)src;
        const s16x8 v1 = *(const s16x8*)(src + 256);
        #pragma unroll
        for (int j = 0; j < 8; ++j) {
            const int col = c8 * 8 + j;
            *(unsigned*)&y1t[img][r2 + 1][col + 1][o2 * 2] =
                (unsigned)(unsigned short)v0[j] | ((unsigned)(unsigned short)v1[j] << 16);
        }
    }
    // stage w_conv -> wt[kk][oc][ic] bf16
    for (int i = t; i < 64 * 32 * 9; i += 256) {
        const int oc = i / 288;
        const int rem = i - oc * 288;
        const int ic = rem / 9;
        const int kk = rem - ic * 9;
        wt[kk][oc][ic] = f2bf(w_conv[i]);
    }
    __syncthreads();

    const int w = t >> 6;                   // image/wave
    const int lane = t & 63;
    const int lc = lane & 15, lg = lane >> 4;

    for (int m4 = 0; m4 < 4; ++m4) {        // 4 chunks of 64 positions
        f32x4 acc[4][4];
        #pragma unroll
        for (int mf = 0; mf < 4; ++mf)
            #pragma unroll
            for (int nf = 0; nf < 4; ++nf) {
                f32x4 z = {0.f, 0.f, 0.f, 0.f};
                acc[mf][nf] = z;
            }
        #pragma unroll
        for (int kk = 0; kk < 9; ++kk) {
            const int di = kk / 3, dj = kk % 3;   // pad already shifts by +1
            s16x8 a[4], bb[4];
            #pragma unroll
            for (int mf = 0; mf < 4; ++mf)
                a[mf] = *(const s16x8*)&y1t[w][m4 * 4 + mf + di][lc + dj][lg * 8];
            #pragma unroll
            for (int nf = 0; nf < 4; ++nf)
                bb[nf] = *(const s16x8*)&wt[kk][nf * 16 + lc][lg * 8];
            #pragma unroll
            for (int mf = 0; mf < 4; ++mf)
                #pragma unroll
                for (int nf = 0; nf < 4; ++nf)
                    acc[mf][nf] = __builtin_amdgcn_mfma_f32_16x16x32_bf16(
                        a[mf], bb[nf], acc[mf][nf], 0, 0, 0);
        }
        // pooled epilogue: imgcol pairs = reg pairs, imgrow pairs = frag pairs
        #pragma unroll
        for (int mfp = 0; mfp < 2; ++mfp) {
            #pragma unroll
            for (int nf = 0; nf < 4; ++nf) {
                const f32x4 u = acc[mfp * 2][nf], v = acc[mfp * 2 + 1][nf];
                const float bbv = b_conv[nf * 16 + lc];
                float q0 = fmaxf(fmaxf(u[0], u[1]), fmaxf(v[0], v[1]));
                float q1 = fmaxf(fmaxf(u[2], u[3]), fmaxf(v[2], v[3]));
                q0 = fmaxf(q0 + bbv, 0.f);
                q1 = fmaxf(q1 + bbv, 0.f);
                const int oc = nf * 16 + lc;
                *(unsigned*)&pbuf[w][oc * 16 + mfp * 8 + lg * 2] =
                    (unsigned)f2bf(q0) | ((unsigned)f2bf(q1) << 16);
            }
        }
        // coalesced bf16 store: p2[b][oc][8][8], this m4 covers rows m4*2..+1
        #pragma unroll
        for (int jj = 0; jj < 2; ++jj) {
            const int u8 = jj * 64 + lane;          // 0..127 units of 8 elems
            const int oc = u8 >> 1, s = (u8 & 1) * 8;
            const s16x8 val = *(const s16x8*)&pbuf[w][u8 * 8];
            *(s16x8*)&p2[((size_t)(b0 + w) * 64 + oc) * 64 + m4 * 16 + s] = val;
        }
    }
}

// ---------------------------------------------------------------------------
// FC1: out(4096,256) = relu(A_bf16(4096,4096) @ W(256,4096)^T + b), fp32 math
// ---------------------------------------------------------------------------
__global__ __launch_bounds__(256) void k_fc1(
    const unsigned short* __restrict__ A, const float* __restrict__ Wt,
    const float* __restrict__ bias, float* __restrict__ out)
{
    __shared__ float As[64][17];
    __shared__ float Bs[64][17];
    const int tx = threadIdx.x & 15, ty = threadIdx.x >> 4;
    const int m0 = blockIdx.x * 64, n0 = blockIdx.y * 64;
    const int lr = threadIdx.x >> 2;
    const int lk = (threadIdx.x & 3) * 4;
    float acc[4][4] = {};
    for (int k0 = 0; k0 < 4096; k0 += 16) {
        const u16x4 av = *(const u16x4*)(A + (size_t)(m0 + lr) * 4096 + k0 + lk);
        const float4 bv = *(const float4*)(Wt + (size_t)(n0 + lr) * 4096 + k0 + lk);
        As[lr][lk + 0] = bf2f(av[0]); As[lr][lk + 1] = bf2f(av[1]);
        As[lr][lk + 2] = bf2f(av[2]); As[lr][lk + 3] = bf2f(av[3]);
        Bs[lr][lk + 0] = bv.x; Bs[lr][lk + 1] = bv.y;
        Bs[lr][lk + 2] = bv.z; Bs[lr][lk + 3] = bv.w;
        __syncthreads();
        #pragma unroll
        for (int kk = 0; kk < 16; ++kk) {
            float a[4], bb[4];
            #pragma unroll
            for (int i = 0; i < 4; ++i) a[i] = As[ty * 4 + i][kk];
            #pragma unroll
            for (int j = 0; j < 4; ++j) bb[j] = Bs[tx * 4 + j][kk];
            #pragma unroll
            for (int i = 0; i < 4; ++i)
                #pragma unroll
                for (int j = 0; j < 4; ++j) acc[i][j] += a[i] * bb[j];
        }
        __syncthreads();
    }
    #pragma unroll
    for (int i = 0; i < 4; ++i) {
        const int m = m0 + ty * 4 + i;
        #pragma unroll
        for (int j = 0; j < 4; ++j) {
            const int n = n0 + tx * 4 + j;
            out[(size_t)m * 256 + n] = fmaxf(acc[i][j] + bias[n], 0.f);
        }
    }
}

// ---------------------------------------------------------------------------
// FC2: out(4096,10) = fc1 @ w_fc2^T + b
// ---------------------------------------------------------------------------
__global__ __launch_bounds__(320) void k_fc2(
    const float* __restrict__ fc1, const float* __restrict__ Wt,
    const float* __restrict__ bias, float* __restrict__ out)
{
    const int t = threadIdx.x;
    const int r = blockIdx.x * 32 + t / 10;
    const int n = t % 10;
    const float4* a = (const float4*)(fc1 + (size_t)r * 256);
    const float4* w = (const float4*)(Wt + (size_t)n * 256);
    float acc = bias[n];
    #pragma unroll 8
    for (int k = 0; k < 64; ++k) {
        const float4 av = a[k], wv = w[k];
        acc += av.x * wv.x + av.y * wv.y + av.z * wv.z + av.w * wv.w;
    }
    out[(size_t)r * 10 + n] = acc;
}

extern "C" void kernel_launch(void* const* d_in, const int* in_sizes, int n_in,
                              void* d_out, int out_size, void* d_ws, size_t ws_size,
                              hipStream_t stream)
{
    const float* x      = (const float*)d_in[0];
    const float* w_lc   = (const float*)d_in[1];
    const float* b_lc   = (const float*)d_in[2];
    const float* w_conv = (const float*)d_in[3];
    const float* b_conv = (const float*)d_in[4];
    const float* w_fc1  = (const float*)d_in[5];
    const float* b_fc1  = (const float*)d_in[6];
    const float* w_fc2  = (const float*)d_in[7];
    const float* b_fc2  = (const float*)d_in[8];
    float* out = (float*)d_out;

    // ws: [p2 bf16 4096x4096 = 33.55 MB][y1g bf16 2048x8192 = 33.55 MB | fc1 f32]
    unsigned short* p2b = (unsigned short*)d_ws;
    unsigned short* y1g = (unsigned short*)((char*)d_ws + 33554432);
    float* fc1 = (float*)((char*)d_ws + 33554432);   // aliases y1g (used after)

    for (int half = 0; half < 2; ++half) {
        k_lc<<<512, 256, 0, stream>>>(x + (size_t)half * 2048 * 3072, w_lc, b_lc, y1g);
        k_conv<<<512, 256, 0, stream>>>(y1g, w_conv, b_conv,
                                        p2b + (size_t)half * 2048 * 4096);
    }
    k_fc1<<<dim3(64, 4), 256, 0, stream>>>(p2b, w_fc1, b_fc1, fc1);
    k_fc2<<<128, 320, 0, stream>>>(fc1, w_fc2, b_fc2, out);
}

// Round 3
// 479.034 us; speedup vs baseline: 11.4326x; 11.4326x over previous
//
#include <hip/hip_runtime.h>

typedef short s16x8 __attribute__((ext_vector_type(8)));
typedef float f32x4 __attribute__((ext_vector_type(4)));
typedef unsigned short u16x4 __attribute__((ext_vector_type(4)));

static __device__ __forceinline__ unsigned short f2bf(float f) {
    union { float f; unsigned u; } v; v.f = f;
    unsigned r = v.u + 0x7FFF + ((v.u >> 16) & 1);   // round-nearest-even
    return (unsigned short)(r >> 16);
}

// ---------------------------------------------------------------------------
// k_prep: one-time weight packing.
//  - Wb   = bf16(w_fc1)   (256,4096)
//  - wt_g = bf16 w_conv packed as [kk][oc][ic-pad40] (zero pad), 46,080 B
// ---------------------------------------------------------------------------
__global__ __launch_bounds__(256) void k_prep(
    const float* __restrict__ w_conv, const float* __restrict__ w_fc1,
    unsigned short* __restrict__ wt_g, unsigned short* __restrict__ Wb)
{
    const int t = threadIdx.x;
    const int gtid = blockIdx.x * 256 + t;
    for (int i = gtid; i < (256 * 4096) / 4; i += gridDim.x * 256) {
        const float4 v = ((const float4*)w_fc1)[i];
        u16x4 o = { f2bf(v.x), f2bf(v.y), f2bf(v.z), f2bf(v.w) };
        *(u16x4*)&Wb[i * 4] = o;
    }
    if (blockIdx.x == 0) {
        for (int i = t; i < 9 * 64 * 40; i += 256) wt_g[i] = 0;
        __syncthreads();
        for (int i = t; i < 64 * 32 * 9; i += 256) {
            const int oc = i / 288;
            const int rem = i - oc * 288;
            const int ic = rem / 9;
            const int kk = rem - ic * 9;
            wt_g[(kk * 64 + oc) * 40 + ic] = f2bf(w_conv[i]);
        }
    }
}

// ---------------------------------------------------------------------------
// k_lc: locally-connected 3x3 + ReLU + maxpool2. 4 images/block, 2 oc/iter.
// Thread t: row r=t>>3, cols c0..c0+3. Coalesced float4 w_lc (each element
// read once per block, 16 FMA per float4). acc live set = 32 regs (no spill).
// Output transposed: y1g[img][pr][pc][o] bf16 (conv-ready, ic-inner).
// ---------------------------------------------------------------------------
__global__ __launch_bounds__(256) void k_lc(
    const float* __restrict__ x,      // (2048,3,32,32) half base
    const float* __restrict__ w_lc,   // (32,3,9,32,32)
    const float* __restrict__ b_lc,   // (32,32,32)
    unsigned short* __restrict__ y1g) // (2048,16,16,32) bf16
{
    __shared__ float xs[4][3][32][33];   // 33-pad: conflict-free row-column reads
    const int t = threadIdx.x;
    const int b0 = blockIdx.x * 4;

    {   // stage 4 images (coalesced float4 read, padded scalar LDS write)
        const float4* s = (const float4*)(x + (size_t)b0 * 3072);
        for (int i = t; i < 3072; i += 256) {
            const float4 v = s[i];
            const int flat = i * 4;
            const int img = flat / 3072;
            const int rem = flat - img * 3072;
            const int c = rem >> 10;
            const int pos = rem & 1023;
            float* d = &xs[img][c][pos >> 5][pos & 31];
            d[0] = v.x; d[1] = v.y; d[2] = v.z; d[3] = v.w;
        }
    }
    __syncthreads();

    const int r = t >> 3;            // 0..31
    const int c0 = (t & 7) * 4;      // 0..28
    const int pr = r >> 1;

    for (int oc2 = 0; oc2 < 16; ++oc2) {
        float acc[2][4][4];
        #pragma unroll
        for (int op = 0; op < 2; ++op) {
            const float4 bv = *(const float4*)&b_lc[((oc2 * 2 + op) * 32 + r) * 32 + c0];
            #pragma unroll
            for (int img = 0; img < 4; ++img) {
                acc[op][img][0] = bv.x; acc[op][img][1] = bv.y;
                acc[op][img][2] = bv.z; acc[op][img][3] = bv.w;
            }
        }
        #pragma unroll
        for (int c = 0; c < 3; ++c) {
            #pragma unroll
            for (int di = 0; di < 3; ++di) {
                const int ii = r + di - 1;
                float xr[4][6];
                if ((unsigned)ii < 32u) {
                    #pragma unroll
                    for (int img = 0; img < 4; ++img) {
                        xr[img][0] = (c0 > 0) ? xs[img][c][ii][c0 - 1] : 0.f;
                        xr[img][1] = xs[img][c][ii][c0 + 0];
                        xr[img][2] = xs[img][c][ii][c0 + 1];
                        xr[img][3] = xs[img][c][ii][c0 + 2];
                        xr[img][4] = xs[img][c][ii][c0 + 3];
                        xr[img][5] = (c0 < 28) ? xs[img][c][ii][c0 + 4] : 0.f;
                    }
                } else {
                    #pragma unroll
                    for (int img = 0; img < 4; ++img)
                        #pragma unroll
                        for (int q = 0; q < 6; ++q) xr[img][q] = 0.f;
                }
                #pragma unroll
                for (int op = 0; op < 2; ++op) {
                    const int o = oc2 * 2 + op;
                    #pragma unroll
                    for (int dj = 0; dj < 3; ++dj) {
                        const float4 wv = *(const float4*)&w_lc[
                            (((size_t)o * 3 + c) * 9 + di * 3 + dj) * 1024 + r * 32 + c0];
                        const float wq[4] = { wv.x, wv.y, wv.z, wv.w };
                        #pragma unroll
                        for (int img = 0; img < 4; ++img)
                            #pragma unroll
                            for (int q = 0; q < 4; ++q)
                                acc[op][img][q] += xr[img][q + dj] * wq[q];
                    }
                }
            }
        }
        // pool 2x2 + relu; store o-pair dwords to transposed layout
        #pragma unroll
        for (int img = 0; img < 4; ++img) {
            float p0[2], p1[2];
            #pragma unroll
            for (int op = 0; op < 2; ++op) {
                const float h0 = fmaxf(acc[op][img][0], acc[op][img][1]);
                const float h1 = fmaxf(acc[op][img][2], acc[op][img][3]);
                const float v0 = __shfl_xor(h0, 8, 64);
                const float v1 = __shfl_xor(h1, 8, 64);
                p0[op] = fmaxf(fmaxf(h0, v0), 0.f);
                p1[op] = fmaxf(fmaxf(h1, v1), 0.f);
            }
            if (!(r & 1)) {
                const size_t base = (size_t)(b0 + img) * 256 + pr * 16;
                const int pc0 = c0 >> 1;
                const unsigned pk0 = (unsigned)f2bf(p0[0]) | ((unsigned)f2bf(p0[1]) << 16);
                const unsigned pk1 = (unsigned)f2bf(p1[0]) | ((unsigned)f2bf(p1[1]) << 16);
                *(unsigned*)&y1g[(base + pc0) * 32 + oc2 * 2] = pk0;
                *(unsigned*)&y1g[(base + pc0 + 1) * 32 + oc2 * 2] = pk1;
            }
        }
    }
}

// ---------------------------------------------------------------------------
// k_conv: 3x3 SAME conv (32->64) + bias + ReLU + maxpool2, bf16 MFMA.
// One image per block; wave w owns position-row chunk m4=w. LDS 80.2 KB ->
// 2 blocks/CU. Same verified fragment algebra as R1.
// ---------------------------------------------------------------------------
__global__ __launch_bounds__(256, 2) void k_conv(
    const unsigned short* __restrict__ y1g,  // (2048,16,16,32) bf16
    const unsigned short* __restrict__ wt_g, // (9,64,40) bf16 packed
    const float* __restrict__ b_conv,        // (64,)
    unsigned short* __restrict__ p2)         // (2048,64,8,8) bf16 half base
{
    __shared__ __align__(16) unsigned short y1t[18][18][40]; // 25,920 B
    __shared__ __align__(16) unsigned short wt[9 * 64 * 40]; // 46,080 B
    __shared__ __align__(16) unsigned short pbuf[4][1024];   //  8,192 B
    const int t = threadIdx.x;
    const int img = blockIdx.x;

    {   // zero y1t (borders + ic pad); copy packed weights
        const s16x8 z = {0, 0, 0, 0, 0, 0, 0, 0};
        unsigned short* p = &y1t[0][0][0];
        for (int i = t * 8; i < 18 * 18 * 40; i += 2048) *(s16x8*)(p + i) = z;
        const s16x8* src = (const s16x8*)wt_g;
        s16x8* dst = (s16x8*)wt;
        for (int i = t; i < (9 * 64 * 40) / 8; i += 256) dst[i] = src[i];
    }
    __syncthreads();
    {   // fill interior: thread t = position (ic-contig copy)
        const int prr = t >> 4, pcc = t & 15;
        const unsigned short* src = y1g + ((size_t)img * 256 + t) * 32;
        unsigned short* d = &y1t[prr + 1][pcc + 1][0];
        #pragma unroll
        for (int ch = 0; ch < 4; ++ch)
            *(s16x8*)(d + ch * 8) = *(const s16x8*)(src + ch * 8);
    }
    __syncthreads();

    const int w = t >> 6, lane = t & 63;
    const int lc = lane & 15, lg = lane >> 4;

    f32x4 acc[4][4];
    #pragma unroll
    for (int mf = 0; mf < 4; ++mf)
        #pragma unroll
        for (int nf = 0; nf < 4; ++nf) {
            f32x4 zz = {0.f, 0.f, 0.f, 0.f};
            acc[mf][nf] = zz;
        }
    #pragma unroll
    for (int kk = 0; kk < 9; ++kk) {
        const int di = kk / 3, dj = kk % 3;
        s16x8 a[4], bb[4];
        #pragma unroll
        for (int mf = 0; mf < 4; ++mf)
            a[mf] = *(const s16x8*)&y1t[w * 4 + mf + di][lc + dj][lg * 8];
        #pragma unroll
        for (int nf = 0; nf < 4; ++nf)
            bb[nf] = *(const s16x8*)&wt[(kk * 64 + nf * 16 + lc) * 40 + lg * 8];
        #pragma unroll
        for (int mf = 0; mf < 4; ++mf)
            #pragma unroll
            for (int nf = 0; nf < 4; ++nf)
                acc[mf][nf] = __builtin_amdgcn_mfma_f32_16x16x32_bf16(
                    a[mf], bb[nf], acc[mf][nf], 0, 0, 0);
    }
    // pooled epilogue (rows via mf pairs, cols via reg pairs)
    #pragma unroll
    for (int mfp = 0; mfp < 2; ++mfp) {
        #pragma unroll
        for (int nf = 0; nf < 4; ++nf) {
            const f32x4 u = acc[mfp * 2][nf], v = acc[mfp * 2 + 1][nf];
            const float bbv = b_conv[nf * 16 + lc];
            float q0 = fmaxf(fmaxf(u[0], u[1]), fmaxf(v[0], v[1]));
            float q1 = fmaxf(fmaxf(u[2], u[3]), fmaxf(v[2], v[3]));
            q0 = fmaxf(q0 + bbv, 0.f);
            q1 = fmaxf(q1 + bbv, 0.f);
            *(unsigned*)&pbuf[w][(nf * 16 + lc) * 16 + mfp * 8 + lg * 2] =
                (unsigned)f2bf(q0) | ((unsigned)f2bf(q1) << 16);
        }
    }
    // per-wave pbuf, same-wave readback: no barrier needed
    #pragma unroll
    for (int jj = 0; jj < 2; ++jj) {
        const int u8 = jj * 64 + lane;
        const int oc = u8 >> 1, s = (u8 & 1) * 8;
        const s16x8 val = *(const s16x8*)&pbuf[w][u8 * 8];
        *(s16x8*)&p2[((size_t)img * 64 + oc) * 64 + w * 16 + s] = val;
    }
}

// ---------------------------------------------------------------------------
// k_fc1: out(4096,256) = relu(A_bf16 @ Wb^T + b) via MFMA.
// BM=64 (4 waves x 16 rows), BN=32 (nf 0..1), BK=64. Grid (64,8)=512 blocks.
// ---------------------------------------------------------------------------
__global__ __launch_bounds__(256) void k_fc1(
    const unsigned short* __restrict__ A,   // (4096,4096) bf16
    const unsigned short* __restrict__ Wb,  // (256,4096) bf16
    const float* __restrict__ bias, float* __restrict__ out)
{
    __shared__ __align__(16) unsigned short As[64][72];
    __shared__ __align__(16) unsigned short Bs[32][72];
    const int t = threadIdx.x;
    const int m0 = blockIdx.x * 64, n0 = blockIdx.y * 32;
    const int w = t >> 6, lane = t & 63;
    const int lc = lane & 15, lg = lane >> 4;
    f32x4 acc[2];
    {
        f32x4 z = {0.f, 0.f, 0.f, 0.f};
        acc[0] = z; acc[1] = z;
    }
    for (int k0 = 0; k0 < 4096; k0 += 64) {
        {
            const int r0 = t >> 3, ch0 = (t & 7) * 8;
            const int id1 = t + 256;
            const int r1 = id1 >> 3, ch1 = (id1 & 7) * 8;
            *(s16x8*)&As[r0][ch0] = *(const s16x8*)&A[(size_t)(m0 + r0) * 4096 + k0 + ch0];
            *(s16x8*)&As[r1][ch1] = *(const s16x8*)&A[(size_t)(m0 + r1) * 4096 + k0 + ch1];
            const int rb = t >> 3, cb = (t & 7) * 8;
            *(s16x8*)&Bs[rb][cb] = *(const s16x8*)&Wb[(size_t)(n0 + rb) * 4096 + k0 + cb];
        }
        __syncthreads();
        #pragma unroll
        for (int kh = 0; kh < 2; ++kh) {
            const s16x8 a  = *(const s16x8*)&As[w * 16 + lc][kh * 32 + lg * 8];
            const s16x8 b0 = *(const s16x8*)&Bs[lc][kh * 32 + lg * 8];
            const s16x8 b1 = *(const s16x8*)&Bs[16 + lc][kh * 32 + lg * 8];
            acc[0] = __builtin_amdgcn_mfma_f32_16x16x32_bf16(a, b0, acc[0], 0, 0, 0);
            acc[1] = __builtin_amdgcn_mfma_f32_16x16x32_bf16(a, b1, acc[1], 0, 0, 0);
        }
        __syncthreads();
    }
    #pragma unroll
    for (int nf = 0; nf < 2; ++nf) {
        const int n = n0 + nf * 16 + lc;
        const float bv = bias[n];
        #pragma unroll
        for (int q = 0; q < 4; ++q) {
            const int m = m0 + w * 16 + lg * 4 + q;
            out[(size_t)m * 256 + n] = fmaxf(acc[nf][q] + bv, 0.f);
        }
    }
}

// ---------------------------------------------------------------------------
// k_fc2: out(4096,10) = fc1 @ w_fc2^T + b
// ---------------------------------------------------------------------------
__global__ __launch_bounds__(320) void k_fc2(
    const float* __restrict__ fc1, const float* __restrict__ Wt,
    const float* __restrict__ bias, float* __restrict__ out)
{
    const int t = threadIdx.x;
    const int r = blockIdx.x * 32 + t / 10;
    const int n = t % 10;
    const float4* a = (const float4*)(fc1 + (size_t)r * 256);
    const float4* w = (const float4*)(Wt + (size_t)n * 256);
    float acc = bias[n];
    #pragma unroll 8
    for (int k = 0; k < 64; ++k) {
        const float4 av = a[k], wv = w[k];
        acc += av.x * wv.x + av.y * wv.y + av.z * wv.z + av.w * wv.w;
    }
    out[(size_t)r * 10 + n] = acc;
}

extern "C" void kernel_launch(void* const* d_in, const int* in_sizes, int n_in,
                              void* d_out, int out_size, void* d_ws, size_t ws_size,
                              hipStream_t stream)
{
    const float* x      = (const float*)d_in[0];
    const float* w_lc   = (const float*)d_in[1];
    const float* b_lc   = (const float*)d_in[2];
    const float* w_conv = (const float*)d_in[3];
    const float* b_conv = (const float*)d_in[4];
    const float* w_fc1  = (const float*)d_in[5];
    const float* b_fc1  = (const float*)d_in[6];
    const float* w_fc2  = (const float*)d_in[7];
    const float* b_fc2  = (const float*)d_in[8];
    float* out = (float*)d_out;

    // ws: [p2b 32MiB][y1g 32MiB | fc1 4MiB][Wb 2MiB][wt_g 46KB] = ~66 MiB
    unsigned short* p2b  = (unsigned short*)d_ws;
    unsigned short* y1g  = (unsigned short*)((char*)d_ws + 33554432);
    float*          fc1  = (float*)((char*)d_ws + 33554432);   // after convs done
    unsigned short* Wb   = (unsigned short*)((char*)d_ws + 67108864);
    unsigned short* wt_g = (unsigned short*)((char*)d_ws + 69206016);

    k_prep<<<64, 256, 0, stream>>>(w_conv, w_fc1, wt_g, Wb);
    for (int half = 0; half < 2; ++half) {
        k_lc<<<512, 256, 0, stream>>>(x + (size_t)half * 2048 * 3072, w_lc, b_lc, y1g);
        k_conv<<<2048, 256, 0, stream>>>(y1g, wt_g, b_conv,
                                         p2b + (size_t)half * 2048 * 4096);
    }
    k_fc1<<<dim3(64, 8), 256, 0, stream>>>(p2b, Wb, b_fc1, fc1);
    k_fc2<<<128, 320, 0, stream>>>(fc1, w_fc2, b_fc2, out);
}

// Round 4
// 268.699 us; speedup vs baseline: 20.3820x; 1.7828x over previous
//
#include <hip/hip_runtime.h>

typedef short s16x8 __attribute__((ext_vector_type(8)));
typedef float f32x4 __attribute__((ext_vector_type(4)));
typedef unsigned short u16x4 __attribute__((ext_vector_type(4)));

static __device__ __forceinline__ unsigned short f2bf(float f) {
    union { float f; unsigned u; } v; v.f = f;
    unsigned r = v.u + 0x7FFF + ((v.u >> 16) & 1);   // round-nearest-even
    return (unsigned short)(r >> 16);
}

// ---------------------------------------------------------------------------
// k_prep (one-time):
//  bx<64   : wpk[pos][o][kpad32] bf16  (per-position LC weights, k=c*9+di*3+dj)
//  64..127 : Wb = bf16(w_fc1) (256,4096)
//  bx==128 : wt_g = bf16 w_conv packed [kk][oc][ic-pad40]
// ---------------------------------------------------------------------------
__global__ __launch_bounds__(256) void k_prep(
    const float* __restrict__ w_lc, const float* __restrict__ w_conv,
    const float* __restrict__ w_fc1, unsigned short* __restrict__ wpk,
    unsigned short* __restrict__ wt_g, unsigned short* __restrict__ Wb)
{
    const int t = threadIdx.x, bx = blockIdx.x;
    if (bx < 64) {
        __shared__ unsigned short wtile[16 * 1024];   // 16 pos x (32o x 32k)
        const int p0 = bx * 16;
        for (int f = t; f < 8192; f += 256) ((int*)wtile)[f] = 0;
        __syncthreads();
        for (int f = t; f < 13824; f += 256) {        // 864 rows x 16 pos
            const int row = f >> 4, pl = f & 15;      // row = o*27 + ck
            const int o = row / 27, ck = row - o * 27;
            wtile[(pl * 32 + o) * 32 + ck] = f2bf(w_lc[(size_t)row * 1024 + p0 + pl]);
        }
        __syncthreads();
        const int4* s = (const int4*)wtile;
        int4* d = (int4*)(wpk + (size_t)p0 * 1024);
        for (int f = t; f < 2048; f += 256) d[f] = s[f];
    } else if (bx < 128) {
        const float4* wf4 = (const float4*)w_fc1;
        for (int f = t; f < 4096; f += 256) {
            const int idx = (bx - 64) * 4096 + f;
            const float4 v = wf4[idx];
            u16x4 o = { f2bf(v.x), f2bf(v.y), f2bf(v.z), f2bf(v.w) };
            *(u16x4*)&Wb[idx * 4] = o;
        }
    } else {
        for (int i = t; i < 9 * 64 * 40; i += 256) wt_g[i] = 0;
        __syncthreads();
        for (int i = t; i < 64 * 32 * 9; i += 256) {
            const int oc = i / 288;
            const int rem = i - oc * 288;
            const int ic = rem / 9;
            const int kk = rem - ic * 9;
            wt_g[(kk * 64 + oc) * 40 + ic] = f2bf(w_conv[i]);
        }
    }
}

// ---------------------------------------------------------------------------
// k_lc (MFMA): per-position GEMM C[img16][oc16] = patch[img][k32] @ w[p][k][oc].
// Block: 32 imgs x 1 pooled row (2 input rows x 32 cols = 64 positions).
// Waves: (mfh=img half, nfh=oc half). Pool = per-lane fmax of 4 position accs.
// ---------------------------------------------------------------------------
__global__ __launch_bounds__(256, 2) void k_lc(
    const float* __restrict__ x,            // quarter (1024,3,32,32)
    const unsigned short* __restrict__ wpk, // (1024,32,32) bf16
    const float* __restrict__ b_lc,         // (32,32,32)
    unsigned short* __restrict__ y1g)       // quarter (1024,16,16,32) bf16
{
    __shared__ unsigned short xb[12 * 34 * 34];   // [c*4+rr][col+1][img] 27.7KB
    __shared__ unsigned short pbuf[16][32][40];   // [jp][img][oc pad] 40KB
    __shared__ float bl[32][2][33];               // bias rows, 8.4KB
    const int t = threadIdx.x;
    const int ib = blockIdx.x >> 4;
    const int pr = blockIdx.x & 15;
    const int img0 = ib * 32;

    for (int f = t; f < 6936; f += 256) ((int*)xb)[f] = 0;
    __syncthreads();
    // x -> xb bf16 (rows 2pr-1 .. 2pr+2, borders stay zero)
    for (int f = t; f < 12288; f += 256) {
        const int img = f / 384;
        const int rem = f - img * 384;
        const int c = rem >> 7;
        const int rr = (rem >> 5) & 3;
        const int col = rem & 31;
        const int xrow = 2 * pr - 1 + rr;
        if ((unsigned)xrow < 32u) {
            const float v = x[((size_t)(img0 + img) * 3 + c) * 1024 + xrow * 32 + col];
            xb[((c * 4 + rr) * 34 + col + 1) * 34 + img] = f2bf(v);
        }
    }
    for (int f = t; f < 2048; f += 256) {
        const int o = f >> 6, ih = (f >> 5) & 1, j = f & 31;
        bl[o][ih][j] = b_lc[(o * 32 + 2 * pr + ih) * 32 + j];
    }
    __syncthreads();

    const int wv = t >> 6, lane = t & 63;
    const int lc = lane & 15, lg = lane >> 4;
    const int mfh = wv >> 1, nfh = wv & 1;
    const int img_l = mfh * 16 + lc;
    const int o = nfh * 16 + lc;

    int abase[8];
    #pragma unroll
    for (int e = 0; e < 8; ++e) {
        int k = lg * 8 + e; if (k > 26) k = 26;   // k>=27: B is zero, A value moot
        const int c = k / 9, dd = k - c * 9, di = dd / 3, dj = dd - di * 3;
        abase[e] = ((c * 4 + di) * 34 + dj) * 34 + img_l;
    }

    s16x8 bf[4];
    #pragma unroll
    for (int pos = 0; pos < 4; ++pos) {
        const int ih = pos >> 1, jc = pos & 1;
        const int p = (2 * pr + ih) * 32 + jc;
        bf[pos] = *(const s16x8*)&wpk[((size_t)p * 32 + o) * 32 + lg * 8];
    }
    for (int jp = 0; jp < 16; ++jp) {
        s16x8 bfn[4];
        if (jp < 15) {
            #pragma unroll
            for (int pos = 0; pos < 4; ++pos) {
                const int ih = pos >> 1, jc = pos & 1;
                const int p = (2 * pr + ih) * 32 + (jp + 1) * 2 + jc;
                bfn[pos] = *(const s16x8*)&wpk[((size_t)p * 32 + o) * 32 + lg * 8];
            }
        }
        f32x4 acc4[4];
        #pragma unroll
        for (int pos = 0; pos < 4; ++pos) {
            const int ih = pos >> 1, jc = pos & 1;
            const int off = ih * 1156 + (jp * 2 + jc) * 34;
            int r[8];
            #pragma unroll
            for (int e = 0; e < 8; ++e) r[e] = xb[abase[e] + off];
            int4 ai = { r[0] | (r[1] << 16), r[2] | (r[3] << 16),
                        r[4] | (r[5] << 16), r[6] | (r[7] << 16) };
            const s16x8 a = __builtin_bit_cast(s16x8, ai);
            f32x4 z = {0.f, 0.f, 0.f, 0.f};
            acc4[pos] = __builtin_amdgcn_mfma_f32_16x16x32_bf16(a, bf[pos], z, 0, 0, 0);
        }
        const float bb0 = bl[o][0][jp * 2], bb1 = bl[o][0][jp * 2 + 1];
        const float bb2 = bl[o][1][jp * 2], bb3 = bl[o][1][jp * 2 + 1];
        #pragma unroll
        for (int q = 0; q < 4; ++q) {
            const float m = fmaxf(fmaxf(fmaxf(acc4[0][q] + bb0, acc4[1][q] + bb1),
                                        fmaxf(acc4[2][q] + bb2, acc4[3][q] + bb3)), 0.f);
            pbuf[jp][mfh * 16 + lg * 4 + q][o] = f2bf(m);
        }
        if (jp < 15) {
            #pragma unroll
            for (int pos = 0; pos < 4; ++pos) bf[pos] = bfn[pos];
        }
    }
    __syncthreads();
    // coalesced y1g write: 512 chunks x 64B, layout [img][pr][jp][oc]
    for (int cidx = t; cidx < 512; cidx += 256) {
        const int img = cidx >> 4, jp = cidx & 15;
        const s16x8* src = (const s16x8*)&pbuf[jp][img][0];
        s16x8* dst = (s16x8*)&y1g[(((size_t)(img0 + img) * 16 + pr) * 16 + jp) * 32];
        #pragma unroll
        for (int u = 0; u < 4; ++u) dst[u] = src[u];
    }
}

// ---------------------------------------------------------------------------
// k_conv: 3x3 SAME conv (32->64) + bias + ReLU + maxpool2, bf16 MFMA.
// ---------------------------------------------------------------------------
__global__ __launch_bounds__(256, 2) void k_conv(
    const unsigned short* __restrict__ y1g,  // quarter (1024,16,16,32) bf16
    const unsigned short* __restrict__ wt_g, // (9,64,40) bf16 packed
    const float* __restrict__ b_conv,        // (64,)
    unsigned short* __restrict__ p2)         // quarter (1024,64,8,8) bf16
{
    __shared__ __align__(16) unsigned short y1t[18][18][40]; // 25,920 B
    __shared__ __align__(16) unsigned short wt[9 * 64 * 40]; // 46,080 B
    __shared__ __align__(16) unsigned short pbuf[4][1024];   //  8,192 B
    const int t = threadIdx.x;
    const int img = blockIdx.x;

    {
        const s16x8 z = {0, 0, 0, 0, 0, 0, 0, 0};
        unsigned short* p = &y1t[0][0][0];
        for (int i = t * 8; i < 18 * 18 * 40; i += 2048) *(s16x8*)(p + i) = z;
        const s16x8* src = (const s16x8*)wt_g;
        s16x8* dst = (s16x8*)wt;
        for (int i = t; i < (9 * 64 * 40) / 8; i += 256) dst[i] = src[i];
    }
    __syncthreads();
    {
        const int prr = t >> 4, pcc = t & 15;
        const unsigned short* src = y1g + ((size_t)img * 256 + t) * 32;
        unsigned short* d = &y1t[prr + 1][pcc + 1][0];
        #pragma unroll
        for (int ch = 0; ch < 4; ++ch)
            *(s16x8*)(d + ch * 8) = *(const s16x8*)(src + ch * 8);
    }
    __syncthreads();

    const int w = t >> 6, lane = t & 63;
    const int lc = lane & 15, lg = lane >> 4;

    f32x4 acc[4][4];
    #pragma unroll
    for (int mf = 0; mf < 4; ++mf)
        #pragma unroll
        for (int nf = 0; nf < 4; ++nf) {
            f32x4 zz = {0.f, 0.f, 0.f, 0.f};
            acc[mf][nf] = zz;
        }
    #pragma unroll
    for (int kk = 0; kk < 9; ++kk) {
        const int di = kk / 3, dj = kk % 3;
        s16x8 a[4], bb[4];
        #pragma unroll
        for (int mf = 0; mf < 4; ++mf)
            a[mf] = *(const s16x8*)&y1t[w * 4 + mf + di][lc + dj][lg * 8];
        #pragma unroll
        for (int nf = 0; nf < 4; ++nf)
            bb[nf] = *(const s16x8*)&wt[(kk * 64 + nf * 16 + lc) * 40 + lg * 8];
        #pragma unroll
        for (int mf = 0; mf < 4; ++mf)
            #pragma unroll
            for (int nf = 0; nf < 4; ++nf)
                acc[mf][nf] = __builtin_amdgcn_mfma_f32_16x16x32_bf16(
                    a[mf], bb[nf], acc[mf][nf], 0, 0, 0);
    }
    #pragma unroll
    for (int mfp = 0; mfp < 2; ++mfp) {
        #pragma unroll
        for (int nf = 0; nf < 4; ++nf) {
            const f32x4 u = acc[mfp * 2][nf], v = acc[mfp * 2 + 1][nf];
            const float bbv = b_conv[nf * 16 + lc];
            float q0 = fmaxf(fmaxf(u[0], u[1]), fmaxf(v[0], v[1]));
            float q1 = fmaxf(fmaxf(u[2], u[3]), fmaxf(v[2], v[3]));
            q0 = fmaxf(q0 + bbv, 0.f);
            q1 = fmaxf(q1 + bbv, 0.f);
            *(unsigned*)&pbuf[w][(nf * 16 + lc) * 16 + mfp * 8 + lg * 2] =
                (unsigned)f2bf(q0) | ((unsigned)f2bf(q1) << 16);
        }
    }
    #pragma unroll
    for (int jj = 0; jj < 2; ++jj) {
        const int u8 = jj * 64 + lane;
        const int oc = u8 >> 1, s = (u8 & 1) * 8;
        const s16x8 val = *(const s16x8*)&pbuf[w][u8 * 8];
        *(s16x8*)&p2[((size_t)img * 64 + oc) * 64 + w * 16 + s] = val;
    }
}

// ---------------------------------------------------------------------------
// k_fc1: out(4096,256) = relu(A_bf16 @ Wb^T + b) via MFMA.
// ---------------------------------------------------------------------------
__global__ __launch_bounds__(256) void k_fc1(
    const unsigned short* __restrict__ A,   // (4096,4096) bf16
    const unsigned short* __restrict__ Wb,  // (256,4096) bf16
    const float* __restrict__ bias, float* __restrict__ out)
{
    __shared__ __align__(16) unsigned short As[64][72];
    __shared__ __align__(16) unsigned short Bs[32][72];
    const int t = threadIdx.x;
    const int m0 = blockIdx.x * 64, n0 = blockIdx.y * 32;
    const int w = t >> 6, lane = t & 63;
    const int lc = lane & 15, lg = lane >> 4;
    f32x4 acc[2];
    {
        f32x4 z = {0.f, 0.f, 0.f, 0.f};
        acc[0] = z; acc[1] = z;
    }
    for (int k0 = 0; k0 < 4096; k0 += 64) {
        {
            const int r0 = t >> 3, ch0 = (t & 7) * 8;
            const int id1 = t + 256;
            const int r1 = id1 >> 3, ch1 = (id1 & 7) * 8;
            *(s16x8*)&As[r0][ch0] = *(const s16x8*)&A[(size_t)(m0 + r0) * 4096 + k0 + ch0];
            *(s16x8*)&As[r1][ch1] = *(const s16x8*)&A[(size_t)(m0 + r1) * 4096 + k0 + ch1];
            const int rb = t >> 3, cb = (t & 7) * 8;
            *(s16x8*)&Bs[rb][cb] = *(const s16x8*)&Wb[(size_t)(n0 + rb) * 4096 + k0 + cb];
        }
        __syncthreads();
        #pragma unroll
        for (int kh = 0; kh < 2; ++kh) {
            const s16x8 a  = *(const s16x8*)&As[w * 16 + lc][kh * 32 + lg * 8];
            const s16x8 b0 = *(const s16x8*)&Bs[lc][kh * 32 + lg * 8];
            const s16x8 b1 = *(const s16x8*)&Bs[16 + lc][kh * 32 + lg * 8];
            acc[0] = __builtin_amdgcn_mfma_f32_16x16x32_bf16(a, b0, acc[0], 0, 0, 0);
            acc[1] = __builtin_amdgcn_mfma_f32_16x16x32_bf16(a, b1, acc[1], 0, 0, 0);
        }
        __syncthreads();
    }
    #pragma unroll
    for (int nf = 0; nf < 2; ++nf) {
        const int n = n0 + nf * 16 + lc;
        const float bv = bias[n];
        #pragma unroll
        for (int q = 0; q < 4; ++q) {
            const int m = m0 + w * 16 + lg * 4 + q;
            out[(size_t)m * 256 + n] = fmaxf(acc[nf][q] + bv, 0.f);
        }
    }
}

// ---------------------------------------------------------------------------
// k_fc2: out(4096,10) = fc1 @ w_fc2^T + b
// ---------------------------------------------------------------------------
__global__ __launch_bounds__(320) void k_fc2(
    const float* __restrict__ fc1, const float* __restrict__ Wt,
    const float* __restrict__ bias, float* __restrict__ out)
{
    const int t = threadIdx.x;
    const int r = blockIdx.x * 32 + t / 10;
    const int n = t % 10;
    const float4* a = (const float4*)(fc1 + (size_t)r * 256);
    const float4* w = (const float4*)(Wt + (size_t)n * 256);
    float acc = bias[n];
    #pragma unroll 8
    for (int k = 0; k < 64; ++k) {
        const float4 av = a[k], wv = w[k];
        acc += av.x * wv.x + av.y * wv.y + av.z * wv.z + av.w * wv.w;
    }
    out[(size_t)r * 10 + n] = acc;
}

extern "C" void kernel_launch(void* const* d_in, const int* in_sizes, int n_in,
                              void* d_out, int out_size, void* d_ws, size_t ws_size,
                              hipStream_t stream)
{
    const float* x      = (const float*)d_in[0];
    const float* w_lc   = (const float*)d_in[1];
    const float* b_lc   = (const float*)d_in[2];
    const float* w_conv = (const float*)d_in[3];
    const float* b_conv = (const float*)d_in[4];
    const float* w_fc1  = (const float*)d_in[5];
    const float* b_fc1  = (const float*)d_in[6];
    const float* w_fc2  = (const float*)d_in[7];
    const float* b_fc2  = (const float*)d_in[8];
    float* out = (float*)d_out;

    // ws layout (bytes):
    //   p2b  @ 0         : 33,554,432 (4096x4096 bf16)
    //   y1g  @ 33,554,432: 16,777,216 (quarter 1024x16x16x32 bf16)
    //   fc1  @ 33,554,432: 4,194,304 f32 (aliases y1g; used after convs)
    //   Wb   @ 50,331,648: 2,097,152
    //   wt_g @ 52,428,800: 46,080
    //   wpk  @ 52,477,952: 2,097,152   -> total ~54.6 MB
    unsigned short* p2b  = (unsigned short*)d_ws;
    unsigned short* y1g  = (unsigned short*)((char*)d_ws + 33554432);
    float*          fc1  = (float*)((char*)d_ws + 33554432);
    unsigned short* Wb   = (unsigned short*)((char*)d_ws + 50331648);
    unsigned short* wt_g = (unsigned short*)((char*)d_ws + 52428800);
    unsigned short* wpk  = (unsigned short*)((char*)d_ws + 52477952);

    k_prep<<<129, 256, 0, stream>>>(w_lc, w_conv, w_fc1, wpk, wt_g, Wb);
    for (int q = 0; q < 4; ++q) {
        k_lc<<<512, 256, 0, stream>>>(x + (size_t)q * 1024 * 3072, wpk, b_lc, y1g);
        k_conv<<<1024, 256, 0, stream>>>(y1g, wt_g, b_conv,
                                         p2b + (size_t)q * 1024 * 4096);
    }
    k_fc1<<<dim3(64, 8), 256, 0, stream>>>(p2b, Wb, b_fc1, fc1);
    k_fc2<<<128, 320, 0, stream>>>(fc1, w_fc2, b_fc2, out);
}

// Round 6
// 199.581 us; speedup vs baseline: 27.4406x; 1.3463x over previous
//
#include <hip/hip_runtime.h>

typedef short s16x8 __attribute__((ext_vector_type(8)));
typedef float f32x4 __attribute__((ext_vector_type(4)));
typedef unsigned short u16x4 __attribute__((ext_vector_type(4)));

static __device__ __forceinline__ unsigned short f2bf(float f) {
    union { float f; unsigned u; } v; v.f = f;
    unsigned r = v.u + 0x7FFF + ((v.u >> 16) & 1);   // round-nearest-even
    return (unsigned short)(r >> 16);
}

// ---------------------------------------------------------------------------
// k_prep (one-time):
//  bx<64   : wpk[pos][o][kpad32] bf16; k=c*9+di*3+dj (27), k=27 = b_lc (bias
//            folded into GEMM), k=28..31 zero
//  64..127 : Wb = bf16(w_fc1) (256,4096)
//  bx==128 : wt_g = bf16 w_conv packed [kk][oc][ic-pad40]
// ---------------------------------------------------------------------------
__global__ __launch_bounds__(256) void k_prep(
    const float* __restrict__ w_lc, const float* __restrict__ b_lc,
    const float* __restrict__ w_conv, const float* __restrict__ w_fc1,
    unsigned short* __restrict__ wpk, unsigned short* __restrict__ wt_g,
    unsigned short* __restrict__ Wb)
{
    const int t = threadIdx.x, bx = blockIdx.x;
    if (bx < 64) {
        __shared__ unsigned short wtile[16 * 1024];   // 16 pos x (32o x 32k)
        const int p0 = bx * 16;
        for (int f = t; f < 8192; f += 256) ((int*)wtile)[f] = 0;
        __syncthreads();
        for (int f = t; f < 13824; f += 256) {        // 864 rows x 16 pos
            const int row = f >> 4, pl = f & 15;      // row = o*27 + ck
            const int o = row / 27, ck = row - o * 27;
            wtile[(pl * 32 + o) * 32 + ck] = f2bf(w_lc[(size_t)row * 1024 + p0 + pl]);
        }
        for (int f = t; f < 512; f += 256) {          // bias slot k=27
            const int o = f >> 4, pl = f & 15;
            wtile[(pl * 32 + o) * 32 + 27] = f2bf(b_lc[o * 1024 + p0 + pl]);
        }
        __syncthreads();
        const int4* s = (const int4*)wtile;
        int4* d = (int4*)(wpk + (size_t)p0 * 1024);
        for (int f = t; f < 2048; f += 256) d[f] = s[f];
    } else if (bx < 128) {
        const float4* wf4 = (const float4*)w_fc1;
        for (int f = t; f < 4096; f += 256) {
            const int idx = (bx - 64) * 4096 + f;
            const float4 v = wf4[idx];
            u16x4 o = { f2bf(v.x), f2bf(v.y), f2bf(v.z), f2bf(v.w) };
            *(u16x4*)&Wb[idx * 4] = o;
        }
    } else {
        for (int i = t; i < 9 * 64 * 40; i += 256) wt_g[i] = 0;
        __syncthreads();
        for (int i = t; i < 64 * 32 * 9; i += 256) {
            const int oc = i / 288;
            const int rem = i - oc * 288;
            const int ic = rem / 9;
            const int kk = rem - ic * 9;
            wt_g[(kk * 64 + oc) * 40 + ic] = f2bf(w_conv[i]);
        }
    }
}

// ---------------------------------------------------------------------------
// k_lc (MFMA): per-position GEMM C[img16][oc32] = patch[img][k28] @ w[p][k][oc]
// Block: 16 imgs x 1 pooled row. Waves: (jp-parity, oc-half). Bias = k:27.
// LDS 24.1 KB -> 5 blocks/CU (20 waves/CU). Pool = fmax of 4 position accs.
// ---------------------------------------------------------------------------
__global__ __launch_bounds__(256, 5) void k_lc(
    const float* __restrict__ x,            // half (2048,3,32,32)
    const unsigned short* __restrict__ wpk, // (1024,32,32) bf16
    unsigned short* __restrict__ y1g)       // half (2048,16,16,32) bf16
{
    __shared__ unsigned short xb[12 * 34 * 17];   // [(c*4+rr)][col+1][img] 13.9KB
    __shared__ unsigned short pbuf[8][16][40];    // [jp&7][img][oc pad] 10.2KB
    const int t = threadIdx.x;
    const int ib = blockIdx.x >> 4;
    const int pr = blockIdx.x & 15;
    const int img0 = ib * 16;

    for (int f = t; f < 3468; f += 256) ((int*)xb)[f] = 0;
    __syncthreads();
    // stage x rows 2pr-1..2pr+2 as bf16 (borders stay zero); coalesced reads
    for (int f = t; f < 6144; f += 256) {
        const int img = f / 384;
        const int rem = f - img * 384;
        const int c = rem >> 7;
        const int rr = (rem >> 5) & 3;
        const int col = rem & 31;
        const int xrow = 2 * pr - 1 + rr;
        if ((unsigned)xrow < 32u) {
            const float v = x[((size_t)(img0 + img) * 3 + c) * 1024 + xrow * 32 + col];
            xb[((c * 4 + rr) * 34 + col + 1) * 17 + img] = f2bf(v);
        }
    }
    __syncthreads();

    const int lane = t & 63, wv = t >> 6;
    const int lc = lane & 15, lg = lane >> 4;
    const int parity = wv & 1, nfh = wv >> 1;
    const int o = nfh * 16 + lc;

    int abase[8];
    #pragma unroll
    for (int e = 0; e < 8; ++e) {
        int k = lg * 8 + e; if (k > 26) k = 26;   // k>=27 handled separately
        const int c = k / 9, dd = k - c * 9, di = dd / 3, dj = dd - di * 3;
        abase[e] = ((c * 4 + di) * 34 + dj) * 17 + lc;
    }

    for (int ph = 0; ph < 2; ++ph) {
        for (int jj = 0; jj < 4; ++jj) {
            const int jp = ph * 8 + jj * 2 + parity;
            s16x8 bfr[4];
            #pragma unroll
            for (int pos = 0; pos < 4; ++pos) {
                const int ih = pos >> 1, jc = pos & 1;
                const int p = (2 * pr + ih) * 32 + jp * 2 + jc;
                bfr[pos] = *(const s16x8*)&wpk[((size_t)p * 32 + o) * 32 + lg * 8];
            }
            f32x4 acc4[4];
            #pragma unroll
            for (int pos = 0; pos < 4; ++pos) {
                const int ih = pos >> 1, jc = pos & 1;
                const int off = ih * 578 + (jp * 2 + jc) * 17;
                int r[8];
                #pragma unroll
                for (int e = 0; e < 8; ++e) r[e] = xb[abase[e] + off];
                if (lg == 3) r[3] = 0x3F80;      // k=27: A=1.0 (bias row)
                int4 ai = { r[0] | (r[1] << 16), r[2] | (r[3] << 16),
                            r[4] | (r[5] << 16), r[6] | (r[7] << 16) };
                const s16x8 a = __builtin_bit_cast(s16x8, ai);
                f32x4 z = {0.f, 0.f, 0.f, 0.f};
                acc4[pos] = __builtin_amdgcn_mfma_f32_16x16x32_bf16(a, bfr[pos], z, 0, 0, 0);
            }
            #pragma unroll
            for (int q = 0; q < 4; ++q) {
                const float m = fmaxf(fmaxf(fmaxf(acc4[0][q], acc4[1][q]),
                                            fmaxf(acc4[2][q], acc4[3][q])), 0.f);
                pbuf[jp & 7][lg * 4 + q][o] = f2bf(m);
            }
        }
        __syncthreads();
        // flush: 16 img x 8 jp x 4 chunks(16B) = 512 chunks, 2 per thread
        for (int c = t; c < 512; c += 256) {
            const int img = c >> 5;
            const int rem = c & 31;
            const int jph = rem >> 2;
            const int u = rem & 3;
            *(s16x8*)&y1g[((((size_t)(img0 + img) * 16 + pr) * 16
                            + ph * 8 + jph) * 32) + u * 8] =
                *(const s16x8*)&pbuf[jph][img][u * 8];
        }
        __syncthreads();
    }
}

// ---------------------------------------------------------------------------
// k_conv: 3x3 SAME conv (32->64) + bias + ReLU + maxpool2, bf16 MFMA.
// ---------------------------------------------------------------------------
__global__ __launch_bounds__(256, 2) void k_conv(
    const unsigned short* __restrict__ y1g,  // half (2048,16,16,32) bf16
    const unsigned short* __restrict__ wt_g, // (9,64,40) bf16 packed
    const float* __restrict__ b_conv,        // (64,)
    unsigned short* __restrict__ p2)         // half (2048,64,8,8) bf16
{
    __shared__ __align__(16) unsigned short y1t[18][18][40]; // 25,920 B
    __shared__ __align__(16) unsigned short wt[9 * 64 * 40]; // 46,080 B
    __shared__ __align__(16) unsigned short pbuf[4][1024];   //  8,192 B
    const int t = threadIdx.x;
    const int img = blockIdx.x;

    {
        const s16x8 z = {0, 0, 0, 0, 0, 0, 0, 0};
        unsigned short* p = &y1t[0][0][0];
        for (int i = t * 8; i < 18 * 18 * 40; i += 2048) *(s16x8*)(p + i) = z;
        const s16x8* src = (const s16x8*)wt_g;
        s16x8* dst = (s16x8*)wt;
        for (int i = t; i < (9 * 64 * 40) / 8; i += 256) dst[i] = src[i];
    }
    __syncthreads();
    {
        const int prr = t >> 4, pcc = t & 15;
        const unsigned short* src = y1g + ((size_t)img * 256 + t) * 32;
        unsigned short* d = &y1t[prr + 1][pcc + 1][0];
        #pragma unroll
        for (int ch = 0; ch < 4; ++ch)
            *(s16x8*)(d + ch * 8) = *(const s16x8*)(src + ch * 8);
    }
    __syncthreads();

    const int w = t >> 6, lane = t & 63;
    const int lc = lane & 15, lg = lane >> 4;

    f32x4 acc[4][4];
    #pragma unroll
    for (int mf = 0; mf < 4; ++mf)
        #pragma unroll
        for (int nf = 0; nf < 4; ++nf) {
            f32x4 zz = {0.f, 0.f, 0.f, 0.f};
            acc[mf][nf] = zz;
        }
    #pragma unroll
    for (int kk = 0; kk < 9; ++kk) {
        const int di = kk / 3, dj = kk % 3;
        s16x8 a[4], bb[4];
        #pragma unroll
        for (int mf = 0; mf < 4; ++mf)
            a[mf] = *(const s16x8*)&y1t[w * 4 + mf + di][lc + dj][lg * 8];
        #pragma unroll
        for (int nf = 0; nf < 4; ++nf)
            bb[nf] = *(const s16x8*)&wt[(kk * 64 + nf * 16 + lc) * 40 + lg * 8];
        #pragma unroll
        for (int mf = 0; mf < 4; ++mf)
            #pragma unroll
            for (int nf = 0; nf < 4; ++nf)
                acc[mf][nf] = __builtin_amdgcn_mfma_f32_16x16x32_bf16(
                    a[mf], bb[nf], acc[mf][nf], 0, 0, 0);
    }
    #pragma unroll
    for (int mfp = 0; mfp < 2; ++mfp) {
        #pragma unroll
        for (int nf = 0; nf < 4; ++nf) {
            const f32x4 u = acc[mfp * 2][nf], v = acc[mfp * 2 + 1][nf];
            const float bbv = b_conv[nf * 16 + lc];
            float q0 = fmaxf(fmaxf(u[0], u[1]), fmaxf(v[0], v[1]));
            float q1 = fmaxf(fmaxf(u[2], u[3]), fmaxf(v[2], v[3]));
            q0 = fmaxf(q0 + bbv, 0.f);
            q1 = fmaxf(q1 + bbv, 0.f);
            *(unsigned*)&pbuf[w][(nf * 16 + lc) * 16 + mfp * 8 + lg * 2] =
                (unsigned)f2bf(q0) | ((unsigned)f2bf(q1) << 16);
        }
    }
    #pragma unroll
    for (int jj = 0; jj < 2; ++jj) {
        const int u8 = jj * 64 + lane;
        const int oc = u8 >> 1, s = (u8 & 1) * 8;
        const s16x8 val = *(const s16x8*)&pbuf[w][u8 * 8];
        *(s16x8*)&p2[((size_t)img * 64 + oc) * 64 + w * 16 + s] = val;
    }
}

// ---------------------------------------------------------------------------
// k_fc1: out(4096,256) = relu(A_bf16 @ Wb^T + b) via MFMA.
// ---------------------------------------------------------------------------
__global__ __launch_bounds__(256) void k_fc1(
    const unsigned short* __restrict__ A,   // (4096,4096) bf16
    const unsigned short* __restrict__ Wb,  // (256,4096) bf16
    const float* __restrict__ bias, float* __restrict__ out)
{
    __shared__ __align__(16) unsigned short As[64][72];
    __shared__ __align__(16) unsigned short Bs[32][72];
    const int t = threadIdx.x;
    const int m0 = blockIdx.x * 64, n0 = blockIdx.y * 32;
    const int w = t >> 6, lane = t & 63;
    const int lc = lane & 15, lg = lane >> 4;
    f32x4 acc[2];
    {
        f32x4 z = {0.f, 0.f, 0.f, 0.f};
        acc[0] = z; acc[1] = z;
    }
    for (int k0 = 0; k0 < 4096; k0 += 64) {
        {
            const int r0 = t >> 3, ch0 = (t & 7) * 8;
            const int id1 = t + 256;
            const int r1 = id1 >> 3, ch1 = (id1 & 7) * 8;
            *(s16x8*)&As[r0][ch0] = *(const s16x8*)&A[(size_t)(m0 + r0) * 4096 + k0 + ch0];
            *(s16x8*)&As[r1][ch1] = *(const s16x8*)&A[(size_t)(m0 + r1) * 4096 + k0 + ch1];
            const int rb = t >> 3, cb = (t & 7) * 8;
            *(s16x8*)&Bs[rb][cb] = *(const s16x8*)&Wb[(size_t)(n0 + rb) * 4096 + k0 + cb];
        }
        __syncthreads();
        #pragma unroll
        for (int kh = 0; kh < 2; ++kh) {
            const s16x8 a  = *(const s16x8*)&As[w * 16 + lc][kh * 32 + lg * 8];
            const s16x8 b0 = *(const s16x8*)&Bs[lc][kh * 32 + lg * 8];
            const s16x8 b1 = *(const s16x8*)&Bs[16 + lc][kh * 32 + lg * 8];
            acc[0] = __builtin_amdgcn_mfma_f32_16x16x32_bf16(a, b0, acc[0], 0, 0, 0);
            acc[1] = __builtin_amdgcn_mfma_f32_16x16x32_bf16(a, b1, acc[1], 0, 0, 0);
        }
        __syncthreads();
    }
    #pragma unroll
    for (int nf = 0; nf < 2; ++nf) {
        const int n = n0 + nf * 16 + lc;
        const float bv = bias[n];
        #pragma unroll
        for (int q = 0; q < 4; ++q) {
            const int m = m0 + w * 16 + lg * 4 + q;
            out[(size_t)m * 256 + n] = fmaxf(acc[nf][q] + bv, 0.f);
        }
    }
}

// ---------------------------------------------------------------------------
// k_fc2: out(4096,10) = fc1 @ w_fc2^T + b
// ---------------------------------------------------------------------------
__global__ __launch_bounds__(320) void k_fc2(
    const float* __restrict__ fc1, const float* __restrict__ Wt,
    const float* __restrict__ bias, float* __restrict__ out)
{
    const int t = threadIdx.x;
    const int r = blockIdx.x * 32 + t / 10;
    const int n = t % 10;
    const float4* a = (const float4*)(fc1 + (size_t)r * 256);
    const float4* w = (const float4*)(Wt + (size_t)n * 256);
    float acc = bias[n];
    #pragma unroll 8
    for (int k = 0; k < 64; ++k) {
        const float4 av = a[k], wv = w[k];
        acc += av.x * wv.x + av.y * wv.y + av.z * wv.z + av.w * wv.w;
    }
    out[(size_t)r * 10 + n] = acc;
}

extern "C" void kernel_launch(void* const* d_in, const int* in_sizes, int n_in,
                              void* d_out, int out_size, void* d_ws, size_t ws_size,
                              hipStream_t stream)
{
    const float* x      = (const float*)d_in[0];
    const float* w_lc   = (const float*)d_in[1];
    const float* b_lc   = (const float*)d_in[2];
    const float* w_conv = (const float*)d_in[3];
    const float* b_conv = (const float*)d_in[4];
    const float* w_fc1  = (const float*)d_in[5];
    const float* b_fc1  = (const float*)d_in[6];
    const float* w_fc2  = (const float*)d_in[7];
    const float* b_fc2  = (const float*)d_in[8];
    float* out = (float*)d_out;

    // ws layout (69.3 MB total):
    //   p2b  @ 0          : 33,554,432  (4096x4096 bf16)
    //   wpk  @ 16,777,216 : 2,097,152   (hides in p2b's 2nd half; clobbered by
    //                                    k_conv half1 only AFTER last wpk read;
    //                                    k_prep rewrites it every launch)
    //   y1g  @ 33,554,432 : 33,554,432  (half 2048x16x16x32 bf16)
    //   fc1  @ 33,554,432 : 4,194,304 f32 (aliases y1g; used after convs)
    //   Wb   @ 67,108,864 : 2,097,152
    //   wt_g @ 69,206,016 : 92,160
    unsigned short* p2b  = (unsigned short*)d_ws;
    unsigned short* wpk  = (unsigned short*)((char*)d_ws + 16777216);
    unsigned short* y1g  = (unsigned short*)((char*)d_ws + 33554432);
    float*          fc1  = (float*)((char*)d_ws + 33554432);
    unsigned short* Wb   = (unsigned short*)((char*)d_ws + 67108864);
    unsigned short* wt_g = (unsigned short*)((char*)d_ws + 69206016);

    k_prep<<<129, 256, 0, stream>>>(w_lc, b_lc, w_conv, w_fc1, wpk, wt_g, Wb);
    for (int half = 0; half < 2; ++half) {
        k_lc<<<2048, 256, 0, stream>>>(x + (size_t)half * 2048 * 3072, wpk, y1g);
        k_conv<<<2048, 256, 0, stream>>>(y1g, wt_g, b_conv,
                                         p2b + (size_t)half * 2048 * 4096);
    }
    k_fc1<<<dim3(64, 8), 256, 0, stream>>>(p2b, Wb, b_fc1, fc1);
    k_fc2<<<128, 320, 0, stream>>>(fc1, w_fc2, b_fc2, out);
}